// Round 5
// baseline (120.864 us; speedup 1.0000x reference)
//
#include <hip/hip_runtime.h>
#include <hip/hip_bf16.h>

#define B_SZ  64
#define N_SZ  512
#define K_SZ  16
#define EMB   128
#define R_TOT (B_SZ * N_SZ)   // 32768 rows

typedef __attribute__((ext_vector_type(8))) short bf16x8;
typedef __attribute__((ext_vector_type(4))) float f32x4;

// XOR-swizzled u16 index into a [*][128]-u16 LDS tile (16B-unit granularity).
// Breaks the 256B-row-stride bank aliasing on ds_read_b128 fragment reads.
#define SWZ(row, col) ((((row) << 7)) + ((((col) >> 3) ^ ((row) & 15)) << 3) + ((col) & 7))

static __device__ __forceinline__ unsigned short f2bf(float x) {
    __hip_bfloat16 h = __float2bfloat16(x);   // RNE
    return *reinterpret_cast<unsigned short*>(&h);
}
static __device__ __forceinline__ float bf2f(unsigned short u) {
    union { unsigned int u32; float f; } c; c.u32 = ((unsigned int)u) << 16; return c.f;
}

// Fused: stage+transpose W_enc; X = word@Wtop + bias (store bf16, pre-relu);
// Y = relu(X)@Wbot (store bf16). Also zeroes cnt[0..63] for the gather kernel.
// block = 64 rows, 256 threads (4 waves). Wave w owns cols [w*32, w*32+32).
__global__ __launch_bounds__(256) void dual_gemm(const float* __restrict__ word,
                                                 const float* __restrict__ W_enc,
                                                 const float* __restrict__ bias,
                                                 unsigned short* __restrict__ Xb,
                                                 unsigned short* __restrict__ Yb,
                                                 int* __restrict__ cnt)
{
    __shared__ unsigned short sA[64 * EMB];          // 16 KB, A-tile (bf16), swizzled
    __shared__ unsigned short sW[2 * EMB * EMB];     // 64 KB, sW[h][e][f] = W_enc[h*128+f][e], swizzled
    const int tid = threadIdx.x;
    const int block_row = blockIdx.x * 64;

    if (blockIdx.x < B_SZ && tid == 0) cnt[blockIdx.x] = 0;   // reset batch counters each call

    // stage + transpose + convert W_enc [256][128] f32 -> sW (bf16, swizzled)
    // 8192 float4s, 32 per thread; 4 u16 LDS scatter-writes each (once per block)
    for (int i = tid; i < 8192; i += 256) {
        const int f  = i >> 5;                 // W_enc row (0..255)
        const int c4 = i & 31;                 // float4 column
        float4 v = ((const float4*)(W_enc + (size_t)f * EMB))[c4];
        unsigned short* base = sW + ((f >> 7) << 14);
        const int fl = f & 127;
        const int e0 = c4 * 4;
        base[SWZ(e0 + 0, fl)] = f2bf(v.x);
        base[SWZ(e0 + 1, fl)] = f2bf(v.y);
        base[SWZ(e0 + 2, fl)] = f2bf(v.z);
        base[SWZ(e0 + 3, fl)] = f2bf(v.w);
    }
    for (int i = tid; i < 2048; i += 256) {          // A tile f32 -> bf16
        int r = i >> 5, c4 = i & 31;                 // col = c4*4 (8B-aligned in-unit)
        float4 v = ((const float4*)(word + (size_t)(block_row + r) * EMB))[c4];
        unsigned short o[4] = { f2bf(v.x), f2bf(v.y), f2bf(v.z), f2bf(v.w) };
        *(uint2*)&sA[SWZ(r, c4 * 4)] = *(uint2*)o;
    }
    __syncthreads();

    const int lane  = tid & 63;
    const int w     = tid >> 6;
    const int l15   = lane & 15;
    const int g     = lane >> 4;                 // 0..3
    const int ncol0 = w * 32;

    f32x4 acc[4][2];
    #pragma unroll
    for (int mb = 0; mb < 4; ++mb)
        #pragma unroll
        for (int nb = 0; nb < 2; ++nb)
            acc[mb][nb] = (f32x4){0.f, 0.f, 0.f, 0.f};

    // ---- GEMM1: sA @ sW[0] ----
    #pragma unroll
    for (int ks = 0; ks < 4; ++ks) {
        bf16x8 a[4], b[2];
        #pragma unroll
        for (int mb = 0; mb < 4; ++mb)
            a[mb] = *(const bf16x8*)&sA[SWZ(mb * 16 + l15, ks * 32 + g * 8)];
        #pragma unroll
        for (int nb = 0; nb < 2; ++nb)
            b[nb] = *(const bf16x8*)&sW[SWZ(ncol0 + nb * 16 + l15, ks * 32 + g * 8)];
        #pragma unroll
        for (int mb = 0; mb < 4; ++mb)
            #pragma unroll
            for (int nb = 0; nb < 2; ++nb)
                acc[mb][nb] = __builtin_amdgcn_mfma_f32_16x16x32_bf16(a[mb], b[nb], acc[mb][nb], 0, 0, 0);
    }
    __syncthreads();   // everyone done READING sA before we overwrite it

    // epilogue 1: X = acc + bias; store Xb (pre-relu); relu into sA for GEMM2
    #pragma unroll
    for (int mb = 0; mb < 4; ++mb) {
        #pragma unroll
        for (int nb = 0; nb < 2; ++nb) {
            const int col = ncol0 + nb * 16 + l15;
            const float bv = bias[col];
            #pragma unroll
            for (int r = 0; r < 4; ++r) {
                const int row_l = mb * 16 + g * 4 + r;
                float x = acc[mb][nb][r] + bv;
                Xb[(size_t)(block_row + row_l) * EMB + col] = f2bf(x);
                sA[SWZ(row_l, col)] = f2bf(fmaxf(x, 0.f));
            }
            acc[mb][nb] = (f32x4){0.f, 0.f, 0.f, 0.f};
        }
    }
    __syncthreads();

    // ---- GEMM2: relu(X) @ sW[1] ----
    #pragma unroll
    for (int ks = 0; ks < 4; ++ks) {
        bf16x8 a[4], b[2];
        #pragma unroll
        for (int mb = 0; mb < 4; ++mb)
            a[mb] = *(const bf16x8*)&sA[SWZ(mb * 16 + l15, ks * 32 + g * 8)];
        #pragma unroll
        for (int nb = 0; nb < 2; ++nb)
            b[nb] = *(const bf16x8*)&sW[(1 << 14) + SWZ(ncol0 + nb * 16 + l15, ks * 32 + g * 8)];
        #pragma unroll
        for (int mb = 0; mb < 4; ++mb)
            #pragma unroll
            for (int nb = 0; nb < 2; ++nb)
                acc[mb][nb] = __builtin_amdgcn_mfma_f32_16x16x32_bf16(a[mb], b[nb], acc[mb][nb], 0, 0, 0);
    }
    #pragma unroll
    for (int mb = 0; mb < 4; ++mb)
        #pragma unroll
        for (int nb = 0; nb < 2; ++nb) {
            const int col = ncol0 + nb * 16 + l15;
            #pragma unroll
            for (int r = 0; r < 4; ++r) {
                const int row_l = mb * 16 + g * 4 + r;
                Yb[(size_t)(block_row + row_l) * EMB + col] = f2bf(acc[mb][nb][r]);
            }
        }
}

// partial[b][chunk][g][e] = sum over group-g's 8 n's of mask * relu(X + mean_k Y[nb]).
// Last chunk-block of each batch (via cnt[b]) reduces 64 partials and does the
// W2 matmul -> out[b]. XCD swizzle: all 16 chunks of batch b land on XCD b&7.
__global__ __launch_bounds__(256) void gather_pool_final(const unsigned short* __restrict__ Xb,
                                                         const unsigned short* __restrict__ Yb,
                                                         const int*   __restrict__ nbr,
                                                         const float* __restrict__ mask,
                                                         const float* __restrict__ W2,
                                                         float* __restrict__ partial,
                                                         int*   __restrict__ cnt,
                                                         float* __restrict__ out)
{
    const int bid   = blockIdx.x;
    const int xcd   = bid & 7;
    const int rest  = bid >> 3;
    const int chunk = rest & 15;
    const int b     = (rest >> 4) * 8 + xcd;
    const int g     = threadIdx.x >> 6;        // 4 groups of 64 lanes
    const int lane  = threadIdx.x & 63;
    const int e0    = lane * 2;
    const unsigned short* Yb_b = Yb + (size_t)b * N_SZ * EMB;

    float s0 = 0.f, s1 = 0.f;
    for (int nn = 0; nn < 8; ++nn) {
        const int n = chunk * 32 + g * 8 + nn;
        const long base = (long)b * N_SZ + n;
        const int* idx = nbr + base * K_SZ;
        int id[K_SZ];
        #pragma unroll
        for (int k = 0; k < K_SZ; ++k) id[k] = idx[k];
        float a0 = 0.f, a1 = 0.f;
        #pragma unroll
        for (int k = 0; k < K_SZ; ++k) {
            unsigned int v = *(const unsigned int*)(Yb_b + (size_t)id[k] * EMB + e0);
            a0 += bf2f((unsigned short)v);
            a1 += bf2f((unsigned short)(v >> 16));
        }
        unsigned int xv = *(const unsigned int*)(Xb + base * EMB + e0);
        const float m = mask[base];
        s0 += fmaxf(bf2f((unsigned short)xv)         + a0 * 0.0625f, 0.f) * m;
        s1 += fmaxf(bf2f((unsigned short)(xv >> 16)) + a1 * 0.0625f, 0.f) * m;
    }
    float2 o = { s0, s1 };
    *(float2*)&partial[(((size_t)b * 16 + chunk) * 4 + g) * EMB + e0] = o;

    // ---- last-block-per-batch: reduce + W2 matmul ----
    __threadfence();                 // release: partials visible device-wide
    __syncthreads();                 // all threads' stores+fences done
    __shared__ int sdone;
    if (threadIdx.x == 0) sdone = (atomicAdd(&cnt[b], 1) == 15) ? 1 : 0;
    __syncthreads();
    if (!sdone) return;
    __threadfence();                 // acquire: see other blocks' partials

    __shared__ float sred[2][EMB];
    const int t    = threadIdx.x;
    const int half = t >> 7;         // 0/1
    const int e    = t & 127;
    const float* pb = partial + (size_t)b * 64 * EMB;
    float s = 0.f;
    #pragma unroll
    for (int c = 0; c < 32; ++c) s += pb[(size_t)(half * 32 + c) * EMB + e];
    sred[half][e] = s;
    __syncthreads();
    if (t < 128) sred[0][t] += sred[1][t];
    __syncthreads();
    if (t < 128) {
        float acc2 = 0.f;
        #pragma unroll 8
        for (int f = 0; f < EMB; ++f) acc2 += sred[0][f] * W2[f * EMB + t];
        out[b * EMB + t] = acc2;
    }
}

extern "C" void kernel_launch(void* const* d_in, const int* in_sizes, int n_in,
                              void* d_out, int out_size, void* d_ws, size_t ws_size,
                              hipStream_t stream)
{
    const float* word  = (const float*)d_in[0];
    const int*   nbr   = (const int*)  d_in[1];
    const float* mask  = (const float*)d_in[2];
    const float* W_enc = (const float*)d_in[3];
    const float* b_enc = (const float*)d_in[4];
    const float* W2    = (const float*)d_in[5];
    float* out = (float*)d_out;

    unsigned short* Xb      = (unsigned short*)d_ws;              // [32768][128] bf16, 8 MB
    unsigned short* Yb      = Xb + (size_t)R_TOT * EMB;           // [32768][128] bf16, 8 MB
    float*          partial = (float*)(Yb + (size_t)R_TOT * EMB); // [64][16][4][128] f32, 2 MB
    int*            cnt     = (int*)(partial + (size_t)B_SZ * 64 * EMB); // [64]

    dual_gemm        <<<R_TOT / 64, 256, 0, stream>>>(word, W_enc, b_enc, Xb, Yb, cnt);
    gather_pool_final<<<B_SZ * 16,  256, 0, stream>>>(Xb, Yb, nbr, mask, W2, partial, cnt, out);
}

// Round 6
// 78.595 us; speedup vs baseline: 1.5378x; 1.5378x over previous
//
#include <hip/hip_runtime.h>
#include <hip/hip_bf16.h>

#define B_SZ  64
#define N_SZ  512
#define K_SZ  16
#define EMB   128

typedef __attribute__((ext_vector_type(8))) short bf16x8;
typedef __attribute__((ext_vector_type(4))) float f32x4;

// XOR-swizzled u16 index into a [*][128]-u16 LDS tile (16B-unit granularity).
// Conflict-free for MFMA fragment ds_read_b128 (16 rows same col-window) AND
// for whole-row gather reads (row-uniform unit permutation).
#define SWZ(row, col) ((((row) << 7)) + ((((col) >> 3) ^ ((row) & 15)) << 3) + ((col) & 7))

static __device__ __forceinline__ unsigned short f2bf(float x) {
    __hip_bfloat16 h = __float2bfloat16(x);   // RNE
    return *reinterpret_cast<unsigned short*>(&h);
}
static __device__ __forceinline__ float bf2f(unsigned short u) {
    union { unsigned int u32; float f; } c; c.u32 = ((unsigned int)u) << 16; return c.f;
}

// One block per batch. 1024 threads = 16 waves; wave w owns rows [32w, 32w+32).
// Phases (only __syncthreads between them, no cross-block comm):
//   0: stage Wtop -> sW (bf16, transposed, swizzled)
//   1: GEMM1  X = word@Wtop + b ; X->global scratch (bf16); relu(X)->sY
//   2: restage Wbot -> sW
//   3: GEMM2  Y = relu(X)@Wbot -> sY in place (wave-private rows)
//   4: gather: agg[n] = mean_k sY[idx[n,k]]; e2 = relu(X[n]+agg); pooled += mask*e2
//   5: cross-wave reduce (sW reused as f32 scratch) + pooled@W2 -> out[b]
__global__ __launch_bounds__(1024, 4) void fused_all(const float* __restrict__ word,
                                                     const int*   __restrict__ nbr,
                                                     const float* __restrict__ mask,
                                                     const float* __restrict__ W_enc,
                                                     const float* __restrict__ b_enc,
                                                     const float* __restrict__ W2,
                                                     unsigned short* __restrict__ Xs,
                                                     float* __restrict__ out)
{
    __shared__ unsigned short sY[N_SZ * EMB];   // 128 KB
    __shared__ unsigned short sW[EMB * EMB];    //  32 KB (one W half at a time)

    const int b    = blockIdx.x;
    const int tid  = threadIdx.x;
    const int lane = tid & 63;
    const int w    = tid >> 6;          // wave 0..15
    const int l15  = lane & 15;
    const int g    = lane >> 4;         // 0..3
    const int row0 = w * 32;            // this wave's rows

    const float* wordb = word + (size_t)b * N_SZ * EMB;
    unsigned short* Xrow = Xs + (size_t)b * N_SZ * EMB;

    // ---- phase 0: stage Wtop (transpose+convert) ----
    {
        const float4* src = (const float4*)W_enc;        // rows 0..127
        for (int i = tid; i < 4096; i += 1024) {
            const int f = i >> 5, c4 = i & 31;
            float4 v = src[f * 32 + c4];
            const int e0 = c4 * 4;
            sW[SWZ(e0 + 0, f)] = f2bf(v.x);
            sW[SWZ(e0 + 1, f)] = f2bf(v.y);
            sW[SWZ(e0 + 2, f)] = f2bf(v.z);
            sW[SWZ(e0 + 3, f)] = f2bf(v.w);
        }
    }
    __syncthreads();

    // ---- phase 1: GEMM1 (A-frags direct from global word) ----
    bf16x8 a_f[2][4];
    #pragma unroll
    for (int mb = 0; mb < 2; ++mb)
        #pragma unroll
        for (int ks = 0; ks < 4; ++ks) {
            const float* p = wordb + (size_t)(row0 + mb * 16 + l15) * EMB + ks * 32 + g * 8;
            float4 v0 = *(const float4*)p;
            float4 v1 = *(const float4*)(p + 4);
            unsigned short t[8] = { f2bf(v0.x), f2bf(v0.y), f2bf(v0.z), f2bf(v0.w),
                                    f2bf(v1.x), f2bf(v1.y), f2bf(v1.z), f2bf(v1.w) };
            a_f[mb][ks] = *(bf16x8*)t;
        }
    #pragma unroll
    for (int np = 0; np < 2; ++np) {
        f32x4 acc[2][4];
        #pragma unroll
        for (int mb = 0; mb < 2; ++mb)
            #pragma unroll
            for (int nb = 0; nb < 4; ++nb)
                acc[mb][nb] = (f32x4){0.f, 0.f, 0.f, 0.f};
        #pragma unroll
        for (int ks = 0; ks < 4; ++ks) {
            bf16x8 bf[4];
            #pragma unroll
            for (int nb = 0; nb < 4; ++nb)
                bf[nb] = *(const bf16x8*)&sW[SWZ(np * 64 + nb * 16 + l15, ks * 32 + g * 8)];
            #pragma unroll
            for (int mb = 0; mb < 2; ++mb)
                #pragma unroll
                for (int nb = 0; nb < 4; ++nb)
                    acc[mb][nb] = __builtin_amdgcn_mfma_f32_16x16x32_bf16(a_f[mb][ks], bf[nb], acc[mb][nb], 0, 0, 0);
        }
        #pragma unroll
        for (int mb = 0; mb < 2; ++mb)
            #pragma unroll
            for (int nb = 0; nb < 4; ++nb) {
                const int col = np * 64 + nb * 16 + l15;
                const float bv = b_enc[col];
                #pragma unroll
                for (int r = 0; r < 4; ++r) {
                    const int row = row0 + mb * 16 + g * 4 + r;
                    float x = acc[mb][nb][r] + bv;
                    Xrow[(size_t)row * EMB + col] = f2bf(x);       // pre-relu X to scratch
                    sY[SWZ(row, col)] = f2bf(fmaxf(x, 0.f));       // E1 into sY
                }
            }
    }
    __syncthreads();                    // all waves done reading sW(top)

    // ---- phase 2: restage Wbot ----
    {
        const float4* src = (const float4*)(W_enc + 128 * EMB);
        for (int i = tid; i < 4096; i += 1024) {
            const int f = i >> 5, c4 = i & 31;
            float4 v = src[f * 32 + c4];
            const int e0 = c4 * 4;
            sW[SWZ(e0 + 0, f)] = f2bf(v.x);
            sW[SWZ(e0 + 1, f)] = f2bf(v.y);
            sW[SWZ(e0 + 2, f)] = f2bf(v.z);
            sW[SWZ(e0 + 3, f)] = f2bf(v.w);
        }
    }
    __syncthreads();

    // ---- phase 3: GEMM2 (A = E1 own rows, read fully into regs, then overwrite in place) ----
    #pragma unroll
    for (int mb = 0; mb < 2; ++mb)
        #pragma unroll
        for (int ks = 0; ks < 4; ++ks)
            a_f[mb][ks] = *(const bf16x8*)&sY[SWZ(row0 + mb * 16 + l15, ks * 32 + g * 8)];
    #pragma unroll
    for (int np = 0; np < 2; ++np) {
        f32x4 acc[2][4];
        #pragma unroll
        for (int mb = 0; mb < 2; ++mb)
            #pragma unroll
            for (int nb = 0; nb < 4; ++nb)
                acc[mb][nb] = (f32x4){0.f, 0.f, 0.f, 0.f};
        #pragma unroll
        for (int ks = 0; ks < 4; ++ks) {
            bf16x8 bf[4];
            #pragma unroll
            for (int nb = 0; nb < 4; ++nb)
                bf[nb] = *(const bf16x8*)&sW[SWZ(np * 64 + nb * 16 + l15, ks * 32 + g * 8)];
            #pragma unroll
            for (int mb = 0; mb < 2; ++mb)
                #pragma unroll
                for (int nb = 0; nb < 4; ++nb)
                    acc[mb][nb] = __builtin_amdgcn_mfma_f32_16x16x32_bf16(a_f[mb][ks], bf[nb], acc[mb][nb], 0, 0, 0);
        }
        #pragma unroll
        for (int mb = 0; mb < 2; ++mb)
            #pragma unroll
            for (int nb = 0; nb < 4; ++nb) {
                const int col = np * 64 + nb * 16 + l15;
                #pragma unroll
                for (int r = 0; r < 4; ++r) {
                    const int row = row0 + mb * 16 + g * 4 + r;
                    sY[SWZ(row, col)] = f2bf(acc[mb][nb][r]);      // Y over E1 (wave-private rows)
                }
            }
    }
    __syncthreads();                    // Y complete; also drains Xrow stores (vmcnt(0) at barrier)

    // ---- phase 4: gather + masked pool (each lane owns cols 2*lane, 2*lane+1) ----
    const int c0 = 2 * lane;
    float s0 = 0.f, s1 = 0.f;
    for (int i = 0; i < 32; ++i) {
        const int n = row0 + i;
        const long base = (long)b * N_SZ + n;
        const int* idx = nbr + base * K_SZ;
        float a0 = 0.f, a1 = 0.f;
        #pragma unroll
        for (int k = 0; k < K_SZ; ++k) {
            const int rr = idx[k];
            unsigned int v = *(const unsigned int*)&sY[SWZ(rr, c0)];
            a0 += bf2f((unsigned short)v);
            a1 += bf2f((unsigned short)(v >> 16));
        }
        unsigned int xv = *(const unsigned int*)&Xrow[(size_t)n * EMB + c0];
        const float m = mask[base];
        s0 += fmaxf(bf2f((unsigned short)xv)         + a0 * 0.0625f, 0.f) * m;
        s1 += fmaxf(bf2f((unsigned short)(xv >> 16)) + a1 * 0.0625f, 0.f) * m;
    }

    // ---- phase 5: cross-wave reduce + W2 matmul (sW reused as f32 scratch) ----
    float* sred = (float*)sW;           // [16][128] partials + [128] pooled = 8.7 KB < 32 KB
    sred[w * EMB + c0]     = s0;
    sred[w * EMB + c0 + 1] = s1;
    __syncthreads();
    if (tid < EMB) {
        float p = 0.f;
        #pragma unroll
        for (int c = 0; c < 16; ++c) p += sred[c * EMB + tid];
        sred[16 * EMB + tid] = p;
    }
    __syncthreads();
    if (tid < EMB) {
        float acc = 0.f;
        #pragma unroll 8
        for (int f = 0; f < EMB; ++f) acc += sred[16 * EMB + f] * W2[f * EMB + tid];
        out[b * EMB + tid] = acc;
    }
}

extern "C" void kernel_launch(void* const* d_in, const int* in_sizes, int n_in,
                              void* d_out, int out_size, void* d_ws, size_t ws_size,
                              hipStream_t stream)
{
    const float* word  = (const float*)d_in[0];
    const int*   nbr   = (const int*)  d_in[1];
    const float* mask  = (const float*)d_in[2];
    const float* W_enc = (const float*)d_in[3];
    const float* b_enc = (const float*)d_in[4];
    const float* W2    = (const float*)d_in[5];
    float* out = (float*)d_out;

    unsigned short* Xs = (unsigned short*)d_ws;   // [64][512][128] bf16 pre-relu X, 8 MB

    fused_all<<<B_SZ, 1024, 0, stream>>>(word, nbr, mask, W_enc, b_enc, W2, Xs, out);
}

// Round 7
// 42.336 us; speedup vs baseline: 2.8549x; 1.8564x over previous
//
#include <hip/hip_runtime.h>
#include <hip/hip_bf16.h>

#define B_SZ  64
#define N_SZ  512
#define K_SZ  16
#define EMB   128
#define R_TOT (B_SZ * N_SZ)   // 32768 rows

typedef __attribute__((ext_vector_type(8))) short bf16x8;
typedef __attribute__((ext_vector_type(4))) float f32x4;

// XOR-swizzled u16 index into a [*][128]-u16 LDS tile (16B-unit granularity).
#define SWZ(row, col) ((((row) << 7)) + ((((col) >> 3) ^ ((row) & 15)) << 3) + ((col) & 7))

static __device__ __forceinline__ unsigned short f2bf(float x) {
    __hip_bfloat16 h = __float2bfloat16(x);   // RNE
    return *reinterpret_cast<unsigned short*>(&h);
}
static __device__ __forceinline__ float bf2f(unsigned short u) {
    union { unsigned int u32; float f; } c; c.u32 = ((unsigned int)u) << 16; return c.f;
}

// W_enc [256][128] f32 -> wt[2][128][128] bf16, transposed: wt[half][e][f] = W_enc[half*128+f][e]
// Also zeroes d_out (gather kernel accumulates into it atomically).
__global__ __launch_bounds__(256) void prep_w(const float* __restrict__ W_enc,
                                              unsigned short* __restrict__ wt,
                                              float* __restrict__ out)
{
    __shared__ float s[16][128];
    const int tid = threadIdx.x;
    const int f0 = blockIdx.x * 16;          // 16 blocks cover 256 f-rows
    for (int i = tid; i < 2048; i += 256) {
        int r = i >> 7, c = i & 127;
        s[r][c] = W_enc[(f0 + r) * EMB + c];
    }
    // zero the output accumulator (B_SZ*EMB = 8192 floats over 16 blocks)
    for (int i = blockIdx.x * 256 + tid; i < B_SZ * EMB; i += 16 * 256) out[i] = 0.f;
    __syncthreads();
    if (tid < 128) {
        const int e = tid;
        unsigned short* dst = wt + ((f0 >= 128) ? (EMB * EMB) : 0) + e * EMB + (f0 & 127);
        for (int j = 0; j < 16; j += 2) {
            unsigned int v = (unsigned int)f2bf(s[j][e]) | ((unsigned int)f2bf(s[j + 1][e]) << 16);
            *(unsigned int*)(dst + j) = v;
        }
    }
}

// Fused: X = word@Wtop + bias (store bf16, pre-relu); Y = relu(X)@Wbot (store bf16)
// block = 64 rows, 256 threads (4 waves). Wave w owns cols [w*32, w*32+32).
// LDS tiles XOR-swizzled (SWZ) so MFMA fragment ds_read_b128 are conflict-free.
__global__ __launch_bounds__(256) void dual_gemm(const float* __restrict__ word,
                                                 const unsigned short* __restrict__ wt,
                                                 const float* __restrict__ bias,
                                                 unsigned short* __restrict__ Xb,
                                                 unsigned short* __restrict__ Yb)
{
    __shared__ unsigned short sA[64 * EMB];          // 16 KB, A-tile (bf16), swizzled
    __shared__ unsigned short sW[2 * EMB * EMB];     // 64 KB, both W halves, swizzled
    const int tid = threadIdx.x;
    const int block_row = blockIdx.x * 64;

    {   // stage both W halves: 4096 uint4; each uint4 = one 16B unit -> swizzled slot
        const uint4* src = (const uint4*)wt;
        for (int i = tid; i < 4096; i += 256) {
            int h = i >> 11, j = i & 2047;
            int e = j >> 4, u = j & 15;
            *(uint4*)&sW[(h << 14) + (e << 7) + ((u ^ (e & 15)) << 3)] = src[i];
        }
    }
    for (int i = tid; i < 2048; i += 256) {          // A tile f32 -> bf16
        int r = i >> 5, c4 = i & 31;
        float4 v = ((const float4*)(word + (size_t)(block_row + r) * EMB))[c4];
        unsigned short o[4] = { f2bf(v.x), f2bf(v.y), f2bf(v.z), f2bf(v.w) };
        *(uint2*)&sA[SWZ(r, c4 * 4)] = *(uint2*)o;
    }
    __syncthreads();

    const int lane  = tid & 63;
    const int w     = tid >> 6;
    const int l15   = lane & 15;
    const int g     = lane >> 4;                 // 0..3
    const int ncol0 = w * 32;

    f32x4 acc[4][2];
    #pragma unroll
    for (int mb = 0; mb < 4; ++mb)
        #pragma unroll
        for (int nb = 0; nb < 2; ++nb)
            acc[mb][nb] = (f32x4){0.f, 0.f, 0.f, 0.f};

    // ---- GEMM1: sA @ sW[0] ----
    #pragma unroll
    for (int ks = 0; ks < 4; ++ks) {
        bf16x8 a[4], b[2];
        #pragma unroll
        for (int mb = 0; mb < 4; ++mb)
            a[mb] = *(const bf16x8*)&sA[SWZ(mb * 16 + l15, ks * 32 + g * 8)];
        #pragma unroll
        for (int nb = 0; nb < 2; ++nb)
            b[nb] = *(const bf16x8*)&sW[SWZ(ncol0 + nb * 16 + l15, ks * 32 + g * 8)];
        #pragma unroll
        for (int mb = 0; mb < 4; ++mb)
            #pragma unroll
            for (int nb = 0; nb < 2; ++nb)
                acc[mb][nb] = __builtin_amdgcn_mfma_f32_16x16x32_bf16(a[mb], b[nb], acc[mb][nb], 0, 0, 0);
    }
    __syncthreads();   // everyone done READING sA before we overwrite it

    // epilogue 1: X = acc + bias; store Xb (pre-relu); relu into sA for GEMM2
    #pragma unroll
    for (int mb = 0; mb < 4; ++mb) {
        #pragma unroll
        for (int nb = 0; nb < 2; ++nb) {
            const int col = ncol0 + nb * 16 + l15;
            const float bv = bias[col];
            #pragma unroll
            for (int r = 0; r < 4; ++r) {
                const int row_l = mb * 16 + g * 4 + r;
                float x = acc[mb][nb][r] + bv;
                Xb[(size_t)(block_row + row_l) * EMB + col] = f2bf(x);
                sA[SWZ(row_l, col)] = f2bf(fmaxf(x, 0.f));
            }
            acc[mb][nb] = (f32x4){0.f, 0.f, 0.f, 0.f};
        }
    }
    __syncthreads();

    // ---- GEMM2: relu(X) @ sW[1] ----
    #pragma unroll
    for (int ks = 0; ks < 4; ++ks) {
        bf16x8 a[4], b[2];
        #pragma unroll
        for (int mb = 0; mb < 4; ++mb)
            a[mb] = *(const bf16x8*)&sA[SWZ(mb * 16 + l15, ks * 32 + g * 8)];
        #pragma unroll
        for (int nb = 0; nb < 2; ++nb)
            b[nb] = *(const bf16x8*)&sW[(1 << 14) + SWZ(ncol0 + nb * 16 + l15, ks * 32 + g * 8)];
        #pragma unroll
        for (int mb = 0; mb < 4; ++mb)
            #pragma unroll
            for (int nb = 0; nb < 2; ++nb)
                acc[mb][nb] = __builtin_amdgcn_mfma_f32_16x16x32_bf16(a[mb], b[nb], acc[mb][nb], 0, 0, 0);
    }
    #pragma unroll
    for (int mb = 0; mb < 4; ++mb)
        #pragma unroll
        for (int nb = 0; nb < 2; ++nb) {
            const int col = ncol0 + nb * 16 + l15;
            #pragma unroll
            for (int r = 0; r < 4; ++r) {
                const int row_l = mb * 16 + g * 4 + r;
                Yb[(size_t)(block_row + row_l) * EMB + col] = f2bf(acc[mb][nb][r]);
            }
        }
}

// Per (b,chunk): 4 groups of 64 lanes; group g sums mask*relu(X + mean_k Y[nb])
// over its 8 n's. Then in-block reduce -> chunk_pool (128), multiply by W2,
// atomicAdd the 128-float result into out[b]  (out = sum_chunks chunk_pool@W2).
// XCD swizzle: all 16 chunks of batch b land on XCD b&7.
__global__ __launch_bounds__(256) void gather_pool_w2(const unsigned short* __restrict__ Xb,
                                                      const unsigned short* __restrict__ Yb,
                                                      const int*   __restrict__ nbr,
                                                      const float* __restrict__ mask,
                                                      const float* __restrict__ W2,
                                                      float* __restrict__ out)
{
    const int bid   = blockIdx.x;
    const int xcd   = bid & 7;
    const int rest  = bid >> 3;
    const int chunk = rest & 15;
    const int b     = (rest >> 4) * 8 + xcd;
    const int g     = threadIdx.x >> 6;        // 4 groups of 64 lanes
    const int lane  = threadIdx.x & 63;
    const int e0    = lane * 2;
    const unsigned short* Yb_b = Yb + (size_t)b * N_SZ * EMB;

    float s0 = 0.f, s1 = 0.f;
    for (int nn = 0; nn < 8; ++nn) {
        const int n = chunk * 32 + g * 8 + nn;
        const long base = (long)b * N_SZ + n;
        const int* idx = nbr + base * K_SZ;
        int id[K_SZ];
        #pragma unroll
        for (int k = 0; k < K_SZ; ++k) id[k] = idx[k];
        float a0 = 0.f, a1 = 0.f;
        #pragma unroll
        for (int k = 0; k < K_SZ; ++k) {
            unsigned int v = *(const unsigned int*)(Yb_b + (size_t)id[k] * EMB + e0);
            a0 += bf2f((unsigned short)v);
            a1 += bf2f((unsigned short)(v >> 16));
        }
        unsigned int xv = *(const unsigned int*)(Xb + base * EMB + e0);
        const float m = mask[base];
        s0 += fmaxf(bf2f((unsigned short)xv)         + a0 * 0.0625f, 0.f) * m;
        s1 += fmaxf(bf2f((unsigned short)(xv >> 16)) + a1 * 0.0625f, 0.f) * m;
    }

    // in-block reduce: 4 group-partials -> chunk_pool[128] in sred[0][*]
    __shared__ float sred[4][EMB];
    sred[g][e0]     = s0;
    sred[g][e0 + 1] = s1;
    __syncthreads();
    const int t = threadIdx.x;
    if (t < EMB) {
        // thread t owns column t exclusively: read rows 0..3, write row 0 — no race
        sred[0][t] = sred[0][t] + sred[1][t] + sred[2][t] + sred[3][t];
    }
    __syncthreads();

    // chunk_pool @ W2 -> atomicAdd into out[b][*]
    if (t < EMB) {
        float r = 0.f;
        #pragma unroll 8
        for (int f = 0; f < EMB; ++f) r += sred[0][f] * W2[f * EMB + t];
        atomicAdd(&out[b * EMB + t], r);
    }
}

extern "C" void kernel_launch(void* const* d_in, const int* in_sizes, int n_in,
                              void* d_out, int out_size, void* d_ws, size_t ws_size,
                              hipStream_t stream)
{
    const float* word  = (const float*)d_in[0];
    const int*   nbr   = (const int*)  d_in[1];
    const float* mask  = (const float*)d_in[2];
    const float* W_enc = (const float*)d_in[3];
    const float* b_enc = (const float*)d_in[4];
    const float* W2    = (const float*)d_in[5];
    float* out = (float*)d_out;

    unsigned short* wt = (unsigned short*)d_ws;          // [2][128][128] bf16, 64 KB
    unsigned short* Xb = wt + 2 * EMB * EMB;             // [32768][128] bf16, 8 MB
    unsigned short* Yb = Xb + (size_t)R_TOT * EMB;       // [32768][128] bf16, 8 MB

    prep_w        <<<16,         256, 0, stream>>>(W_enc, wt, out);
    dual_gemm     <<<R_TOT / 64, 256, 0, stream>>>(word, wt, b_enc, Xb, Yb);
    gather_pool_w2<<<B_SZ * 16,  256, 0, stream>>>(Xb, Yb, nbr, mask, W2, out);
}

// Round 8
// 37.794 us; speedup vs baseline: 3.1980x; 1.1202x over previous
//
#include <hip/hip_runtime.h>
#include <hip/hip_bf16.h>

#define B_SZ  64
#define N_SZ  512
#define K_SZ  16
#define EMB   128
#define R_TOT (B_SZ * N_SZ)   // 32768 rows

typedef __attribute__((ext_vector_type(8))) short bf16x8;
typedef __attribute__((ext_vector_type(4))) float f32x4;

// XOR-swizzled u16 index into a [*][128]-u16 LDS tile (16B-unit granularity).
#define SWZ(row, col) ((((row) << 7)) + ((((col) >> 3) ^ ((row) & 15)) << 3) + ((col) & 7))

static __device__ __forceinline__ unsigned short f2bf(float x) {
    __hip_bfloat16 h = __float2bfloat16(x);   // RNE
    return *reinterpret_cast<unsigned short*>(&h);
}
static __device__ __forceinline__ float bf2f(unsigned short u) {
    union { unsigned int u32; float f; } c; c.u32 = ((unsigned int)u) << 16; return c.f;
}

// W_enc [256][128] f32 -> wt[2][128][128] bf16, transposed: wt[half][e][f] = W_enc[half*128+f][e]
// Also zeroes d_out (gather kernel accumulates into it atomically).
__global__ __launch_bounds__(256) void prep_w(const float* __restrict__ W_enc,
                                              unsigned short* __restrict__ wt,
                                              float* __restrict__ out)
{
    __shared__ float s[16][128];
    const int tid = threadIdx.x;
    const int f0 = blockIdx.x * 16;          // 16 blocks cover 256 f-rows
    for (int i = tid; i < 2048; i += 256) {
        int r = i >> 7, c = i & 127;
        s[r][c] = W_enc[(f0 + r) * EMB + c];
    }
    // zero the output accumulator (B_SZ*EMB = 8192 floats over 16 blocks)
    for (int i = blockIdx.x * 256 + tid; i < B_SZ * EMB; i += 16 * 256) out[i] = 0.f;
    __syncthreads();
    if (tid < 128) {
        const int e = tid;
        unsigned short* dst = wt + ((f0 >= 128) ? (EMB * EMB) : 0) + e * EMB + (f0 & 127);
        for (int j = 0; j < 16; j += 2) {
            unsigned int v = (unsigned int)f2bf(s[j][e]) | ((unsigned int)f2bf(s[j + 1][e]) << 16);
            *(unsigned int*)(dst + j) = v;
        }
    }
}

// Fused: X = word@Wtop + bias (store bf16, pre-relu); Y = relu(X)@Wbot (store bf16)
// block = 64 rows, 256 threads (4 waves). Wave w owns cols [w*32, w*32+32).
// XCD-affine block map: all 8 row-blocks of batch b run on XCD b&7, so batch b's
// X/Y land in the SAME per-XCD L2 that gather_pool_w2 (also swizzled) reads from.
__global__ __launch_bounds__(256) void dual_gemm(const float* __restrict__ word,
                                                 const unsigned short* __restrict__ wt,
                                                 const float* __restrict__ bias,
                                                 unsigned short* __restrict__ Xb,
                                                 unsigned short* __restrict__ Yb)
{
    __shared__ unsigned short sA[64 * EMB];          // 16 KB, A-tile (bf16), swizzled
    __shared__ unsigned short sW[2 * EMB * EMB];     // 64 KB, both W halves, swizzled
    const int tid = threadIdx.x;

    // bid -> (batch, row-chunk) with batch&7 == bid&7 (XCD heuristic: bid%8)
    const int bid    = blockIdx.x;
    const int xcd    = bid & 7;
    const int j      = bid >> 3;            // 0..63
    const int b      = xcd + 8 * (j & 7);   // 0..63, b&7 == xcd
    const int rchunk = j >> 3;              // 0..7
    const int block_row = b * N_SZ + rchunk * 64;

    {   // stage both W halves: 4096 uint4; each uint4 = one 16B unit -> swizzled slot
        const uint4* src = (const uint4*)wt;
        for (int i = tid; i < 4096; i += 256) {
            int h = i >> 11, jj = i & 2047;
            int e = jj >> 4, u = jj & 15;
            *(uint4*)&sW[(h << 14) + (e << 7) + ((u ^ (e & 15)) << 3)] = src[i];
        }
    }
    for (int i = tid; i < 2048; i += 256) {          // A tile f32 -> bf16
        int r = i >> 5, c4 = i & 31;
        float4 v = ((const float4*)(word + (size_t)(block_row + r) * EMB))[c4];
        unsigned short o[4] = { f2bf(v.x), f2bf(v.y), f2bf(v.z), f2bf(v.w) };
        *(uint2*)&sA[SWZ(r, c4 * 4)] = *(uint2*)o;
    }
    __syncthreads();

    const int lane  = tid & 63;
    const int w     = tid >> 6;
    const int l15   = lane & 15;
    const int g     = lane >> 4;                 // 0..3
    const int ncol0 = w * 32;

    f32x4 acc[4][2];
    #pragma unroll
    for (int mb = 0; mb < 4; ++mb)
        #pragma unroll
        for (int nb = 0; nb < 2; ++nb)
            acc[mb][nb] = (f32x4){0.f, 0.f, 0.f, 0.f};

    // ---- GEMM1: sA @ sW[0] ----
    #pragma unroll
    for (int ks = 0; ks < 4; ++ks) {
        bf16x8 a[4], bfr[2];
        #pragma unroll
        for (int mb = 0; mb < 4; ++mb)
            a[mb] = *(const bf16x8*)&sA[SWZ(mb * 16 + l15, ks * 32 + g * 8)];
        #pragma unroll
        for (int nb = 0; nb < 2; ++nb)
            bfr[nb] = *(const bf16x8*)&sW[SWZ(ncol0 + nb * 16 + l15, ks * 32 + g * 8)];
        #pragma unroll
        for (int mb = 0; mb < 4; ++mb)
            #pragma unroll
            for (int nb = 0; nb < 2; ++nb)
                acc[mb][nb] = __builtin_amdgcn_mfma_f32_16x16x32_bf16(a[mb], bfr[nb], acc[mb][nb], 0, 0, 0);
    }
    __syncthreads();   // everyone done READING sA before we overwrite it

    // epilogue 1: X = acc + bias; store Xb (pre-relu); relu into sA for GEMM2
    #pragma unroll
    for (int mb = 0; mb < 4; ++mb) {
        #pragma unroll
        for (int nb = 0; nb < 2; ++nb) {
            const int col = ncol0 + nb * 16 + l15;
            const float bv = bias[col];
            #pragma unroll
            for (int r = 0; r < 4; ++r) {
                const int row_l = mb * 16 + g * 4 + r;
                float x = acc[mb][nb][r] + bv;
                Xb[(size_t)(block_row + row_l) * EMB + col] = f2bf(x);
                sA[SWZ(row_l, col)] = f2bf(fmaxf(x, 0.f));
            }
            acc[mb][nb] = (f32x4){0.f, 0.f, 0.f, 0.f};
        }
    }
    __syncthreads();

    // ---- GEMM2: relu(X) @ sW[1] ----
    #pragma unroll
    for (int ks = 0; ks < 4; ++ks) {
        bf16x8 a[4], bfr[2];
        #pragma unroll
        for (int mb = 0; mb < 4; ++mb)
            a[mb] = *(const bf16x8*)&sA[SWZ(mb * 16 + l15, ks * 32 + g * 8)];
        #pragma unroll
        for (int nb = 0; nb < 2; ++nb)
            bfr[nb] = *(const bf16x8*)&sW[(1 << 14) + SWZ(ncol0 + nb * 16 + l15, ks * 32 + g * 8)];
        #pragma unroll
        for (int mb = 0; mb < 4; ++mb)
            #pragma unroll
            for (int nb = 0; nb < 2; ++nb)
                acc[mb][nb] = __builtin_amdgcn_mfma_f32_16x16x32_bf16(a[mb], bfr[nb], acc[mb][nb], 0, 0, 0);
    }
    #pragma unroll
    for (int mb = 0; mb < 4; ++mb)
        #pragma unroll
        for (int nb = 0; nb < 2; ++nb) {
            const int col = ncol0 + nb * 16 + l15;
            #pragma unroll
            for (int r = 0; r < 4; ++r) {
                const int row_l = mb * 16 + g * 4 + r;
                Yb[(size_t)(block_row + row_l) * EMB + col] = f2bf(acc[mb][nb][r]);
            }
        }
}

// Per (b,chunk): 4 groups of 64 lanes; group g sums mask*relu(X + mean_k Y[nb])
// over its 8 n's. In-block reduce -> chunk_pool (128), multiply by W2,
// atomicAdd the 128-float result into out[b]. XCD swizzle: batch b on XCD b&7
// (matches dual_gemm's producer map -> Y/X reads hit the local L2).
__global__ __launch_bounds__(256) void gather_pool_w2(const unsigned short* __restrict__ Xb,
                                                      const unsigned short* __restrict__ Yb,
                                                      const int*   __restrict__ nbr,
                                                      const float* __restrict__ mask,
                                                      const float* __restrict__ W2,
                                                      float* __restrict__ out)
{
    const int bid   = blockIdx.x;
    const int xcd   = bid & 7;
    const int rest  = bid >> 3;
    const int chunk = rest & 15;
    const int b     = (rest >> 4) * 8 + xcd;
    const int g     = threadIdx.x >> 6;        // 4 groups of 64 lanes
    const int lane  = threadIdx.x & 63;
    const int e0    = lane * 2;
    const unsigned short* Yb_b = Yb + (size_t)b * N_SZ * EMB;

    float s0 = 0.f, s1 = 0.f;
    for (int nn = 0; nn < 8; ++nn) {
        const int n = chunk * 32 + g * 8 + nn;
        const long base = (long)b * N_SZ + n;
        const int* idx = nbr + base * K_SZ;
        int id[K_SZ];
        #pragma unroll
        for (int k = 0; k < K_SZ; ++k) id[k] = idx[k];
        float a0 = 0.f, a1 = 0.f;
        #pragma unroll
        for (int k = 0; k < K_SZ; ++k) {
            unsigned int v = *(const unsigned int*)(Yb_b + (size_t)id[k] * EMB + e0);
            a0 += bf2f((unsigned short)v);
            a1 += bf2f((unsigned short)(v >> 16));
        }
        unsigned int xv = *(const unsigned int*)(Xb + base * EMB + e0);
        const float m = mask[base];
        s0 += fmaxf(bf2f((unsigned short)xv)         + a0 * 0.0625f, 0.f) * m;
        s1 += fmaxf(bf2f((unsigned short)(xv >> 16)) + a1 * 0.0625f, 0.f) * m;
    }

    // in-block reduce: 4 group-partials -> chunk_pool[128] in sred[0][*]
    __shared__ float sred[4][EMB];
    sred[g][e0]     = s0;
    sred[g][e0 + 1] = s1;
    __syncthreads();
    const int t = threadIdx.x;
    if (t < EMB) {
        // thread t owns column t exclusively: read rows 0..3, write row 0 — no race
        sred[0][t] = sred[0][t] + sred[1][t] + sred[2][t] + sred[3][t];
    }
    __syncthreads();

    // chunk_pool @ W2 -> atomicAdd into out[b][*]
    if (t < EMB) {
        float r = 0.f;
        #pragma unroll 8
        for (int f = 0; f < EMB; ++f) r += sred[0][f] * W2[f * EMB + t];
        atomicAdd(&out[b * EMB + t], r);
    }
}

extern "C" void kernel_launch(void* const* d_in, const int* in_sizes, int n_in,
                              void* d_out, int out_size, void* d_ws, size_t ws_size,
                              hipStream_t stream)
{
    const float* word  = (const float*)d_in[0];
    const int*   nbr   = (const int*)  d_in[1];
    const float* mask  = (const float*)d_in[2];
    const float* W_enc = (const float*)d_in[3];
    const float* b_enc = (const float*)d_in[4];
    const float* W2    = (const float*)d_in[5];
    float* out = (float*)d_out;

    unsigned short* wt = (unsigned short*)d_ws;          // [2][128][128] bf16, 64 KB
    unsigned short* Xb = wt + 2 * EMB * EMB;             // [32768][128] bf16, 8 MB
    unsigned short* Yb = Xb + (size_t)R_TOT * EMB;       // [32768][128] bf16, 8 MB

    prep_w        <<<16,         256, 0, stream>>>(W_enc, wt, out);
    dual_gemm     <<<R_TOT / 64, 256, 0, stream>>>(word, wt, b_enc, Xb, Yb);
    gather_pool_w2<<<B_SZ * 16,  256, 0, stream>>>(Xb, Yb, nbr, mask, W2, out);
}

// Round 9
// 36.864 us; speedup vs baseline: 3.2786x; 1.0252x over previous
//
#include <hip/hip_runtime.h>
#include <hip/hip_bf16.h>

#define B_SZ  64
#define N_SZ  512
#define K_SZ  16
#define EMB   128
#define R_TOT (B_SZ * N_SZ)   // 32768 rows

typedef __attribute__((ext_vector_type(8))) short bf16x8;
typedef __attribute__((ext_vector_type(4))) float f32x4;

// XOR-swizzled u16 index into a [*][128]-u16 LDS tile (16B-unit granularity).
#define SWZ(row, col) ((((row) << 7)) + ((((col) >> 3) ^ ((row) & 15)) << 3) + ((col) & 7))

static __device__ __forceinline__ unsigned short f2bf(float x) {
    __hip_bfloat16 h = __float2bfloat16(x);   // RNE
    return *reinterpret_cast<unsigned short*>(&h);
}
static __device__ __forceinline__ float bf2f(unsigned short u) {
    union { unsigned int u32; float f; } c; c.u32 = ((unsigned int)u) << 16; return c.f;
}

// W_enc [256][128] f32 -> wt[2][128][128] bf16, transposed: wt[half][e][f] = W_enc[half*128+f][e]
// Also zeroes d_out (gather kernel accumulates into it atomically).
__global__ __launch_bounds__(256) void prep_w(const float* __restrict__ W_enc,
                                              unsigned short* __restrict__ wt,
                                              float* __restrict__ out)
{
    __shared__ float s[16][128];
    const int tid = threadIdx.x;
    const int f0 = blockIdx.x * 16;          // 16 blocks cover 256 f-rows
    for (int i = tid; i < 2048; i += 256) {
        int r = i >> 7, c = i & 127;
        s[r][c] = W_enc[(f0 + r) * EMB + c];
    }
    // zero the output accumulator (B_SZ*EMB = 8192 floats over 16 blocks)
    for (int i = blockIdx.x * 256 + tid; i < B_SZ * EMB; i += 16 * 256) out[i] = 0.f;
    __syncthreads();
    if (tid < 128) {
        const int e = tid;
        unsigned short* dst = wt + ((f0 >= 128) ? (EMB * EMB) : 0) + e * EMB + (f0 & 127);
        for (int j = 0; j < 16; j += 2) {
            unsigned int v = (unsigned int)f2bf(s[j][e]) | ((unsigned int)f2bf(s[j + 1][e]) << 16);
            *(unsigned int*)(dst + j) = v;
        }
    }
}

// Fused: X = word@Wtop + bias (store bf16, pre-relu); Y = relu(X)@Wbot (store bf16)
// block = 64 rows, 256 threads (4 waves). Wave w owns cols [w*32, w*32+32).
// B-fragments load DIRECTLY from global wt (L2-hot, contiguous 16B each) — no sW
// LDS tile. LDS holds only the A-tile, double-buffered: sA0 = bf16(word),
// sA1 = relu(X). XCD-affine block map matches gather (batch b on XCD b&7).
__global__ __launch_bounds__(256) void dual_gemm(const float* __restrict__ word,
                                                 const unsigned short* __restrict__ wt,
                                                 const float* __restrict__ bias,
                                                 unsigned short* __restrict__ Xb,
                                                 unsigned short* __restrict__ Yb)
{
    __shared__ unsigned short sA0[64 * EMB];   // 16 KB, bf16(word) tile, swizzled
    __shared__ unsigned short sA1[64 * EMB];   // 16 KB, relu(X) tile, swizzled
    const int tid = threadIdx.x;

    // bid -> (batch, row-chunk) with batch&7 == bid&7 (XCD heuristic: bid%8)
    const int bid    = blockIdx.x;
    const int xcd    = bid & 7;
    const int j      = bid >> 3;            // 0..63
    const int b      = xcd + 8 * (j & 7);   // 0..63, b&7 == xcd
    const int rchunk = j >> 3;              // 0..7
    const int block_row = b * N_SZ + rchunk * 64;

    for (int i = tid; i < 2048; i += 256) {          // A tile f32 -> bf16
        int r = i >> 5, c4 = i & 31;
        float4 v = ((const float4*)(word + (size_t)(block_row + r) * EMB))[c4];
        unsigned short o[4] = { f2bf(v.x), f2bf(v.y), f2bf(v.z), f2bf(v.w) };
        *(uint2*)&sA0[SWZ(r, c4 * 4)] = *(uint2*)o;
    }

    const int lane  = tid & 63;
    const int w     = tid >> 6;
    const int l15   = lane & 15;
    const int g     = lane >> 4;                 // 0..3
    const int ncol0 = w * 32;

    // B fragments for GEMM1, straight from global wt (each 16B contiguous)
    bf16x8 bfr[2][4];
    #pragma unroll
    for (int nb = 0; nb < 2; ++nb)
        #pragma unroll
        for (int ks = 0; ks < 4; ++ks)
            bfr[nb][ks] = *(const bf16x8*)&wt[(size_t)(ncol0 + nb * 16 + l15) * EMB + ks * 32 + g * 8];

    f32x4 acc[4][2];
    #pragma unroll
    for (int mb = 0; mb < 4; ++mb)
        #pragma unroll
        for (int nb = 0; nb < 2; ++nb)
            acc[mb][nb] = (f32x4){0.f, 0.f, 0.f, 0.f};

    __syncthreads();   // sA0 staged

    // ---- GEMM1: sA0 @ Wtop ----
    #pragma unroll
    for (int ks = 0; ks < 4; ++ks) {
        bf16x8 a[4];
        #pragma unroll
        for (int mb = 0; mb < 4; ++mb)
            a[mb] = *(const bf16x8*)&sA0[SWZ(mb * 16 + l15, ks * 32 + g * 8)];
        #pragma unroll
        for (int mb = 0; mb < 4; ++mb)
            #pragma unroll
            for (int nb = 0; nb < 2; ++nb)
                acc[mb][nb] = __builtin_amdgcn_mfma_f32_16x16x32_bf16(a[mb], bfr[nb][ks], acc[mb][nb], 0, 0, 0);
    }

    // prefetch GEMM2 B fragments (overlaps with epilogue stores)
    bf16x8 bfr2[2][4];
    #pragma unroll
    for (int nb = 0; nb < 2; ++nb)
        #pragma unroll
        for (int ks = 0; ks < 4; ++ks)
            bfr2[nb][ks] = *(const bf16x8*)&wt[(size_t)EMB * EMB + (size_t)(ncol0 + nb * 16 + l15) * EMB + ks * 32 + g * 8];

    // epilogue 1: X = acc + bias; store Xb (pre-relu); relu into sA1 (no sync needed:
    // sA1 is a different buffer than the one GEMM1 reads)
    #pragma unroll
    for (int mb = 0; mb < 4; ++mb) {
        #pragma unroll
        for (int nb = 0; nb < 2; ++nb) {
            const int col = ncol0 + nb * 16 + l15;
            const float bv = bias[col];
            #pragma unroll
            for (int r = 0; r < 4; ++r) {
                const int row_l = mb * 16 + g * 4 + r;
                float x = acc[mb][nb][r] + bv;
                Xb[(size_t)(block_row + row_l) * EMB + col] = f2bf(x);
                sA1[SWZ(row_l, col)] = f2bf(fmaxf(x, 0.f));
            }
            acc[mb][nb] = (f32x4){0.f, 0.f, 0.f, 0.f};
        }
    }
    __syncthreads();   // sA1 complete

    // ---- GEMM2: relu(X) @ Wbot ----
    #pragma unroll
    for (int ks = 0; ks < 4; ++ks) {
        bf16x8 a[4];
        #pragma unroll
        for (int mb = 0; mb < 4; ++mb)
            a[mb] = *(const bf16x8*)&sA1[SWZ(mb * 16 + l15, ks * 32 + g * 8)];
        #pragma unroll
        for (int mb = 0; mb < 4; ++mb)
            #pragma unroll
            for (int nb = 0; nb < 2; ++nb)
                acc[mb][nb] = __builtin_amdgcn_mfma_f32_16x16x32_bf16(a[mb], bfr2[nb][ks], acc[mb][nb], 0, 0, 0);
    }
    #pragma unroll
    for (int mb = 0; mb < 4; ++mb)
        #pragma unroll
        for (int nb = 0; nb < 2; ++nb) {
            const int col = ncol0 + nb * 16 + l15;
            #pragma unroll
            for (int r = 0; r < 4; ++r) {
                const int row_l = mb * 16 + g * 4 + r;
                Yb[(size_t)(block_row + row_l) * EMB + col] = f2bf(acc[mb][nb][r]);
            }
        }
}

// Per (b,chunk): 4 groups of 64 lanes; group g sums mask*relu(X + mean_k Y[nb])
// over its 8 n's. In-block reduce -> chunk_pool (128), multiply by W2,
// atomicAdd the 128-float result into out[b]. XCD swizzle: batch b on XCD b&7
// (matches dual_gemm's producer map -> Y/X reads hit the local L2).
__global__ __launch_bounds__(256) void gather_pool_w2(const unsigned short* __restrict__ Xb,
                                                      const unsigned short* __restrict__ Yb,
                                                      const int*   __restrict__ nbr,
                                                      const float* __restrict__ mask,
                                                      const float* __restrict__ W2,
                                                      float* __restrict__ out)
{
    const int bid   = blockIdx.x;
    const int xcd   = bid & 7;
    const int rest  = bid >> 3;
    const int chunk = rest & 15;
    const int b     = (rest >> 4) * 8 + xcd;
    const int g     = threadIdx.x >> 6;        // 4 groups of 64 lanes
    const int lane  = threadIdx.x & 63;
    const int e0    = lane * 2;
    const unsigned short* Yb_b = Yb + (size_t)b * N_SZ * EMB;

    float s0 = 0.f, s1 = 0.f;
    for (int nn = 0; nn < 8; ++nn) {
        const int n = chunk * 32 + g * 8 + nn;
        const long base = (long)b * N_SZ + n;
        const int* idx = nbr + base * K_SZ;
        int id[K_SZ];
        #pragma unroll
        for (int k = 0; k < K_SZ; ++k) id[k] = idx[k];
        float a0 = 0.f, a1 = 0.f;
        #pragma unroll
        for (int k = 0; k < K_SZ; ++k) {
            unsigned int v = *(const unsigned int*)(Yb_b + (size_t)id[k] * EMB + e0);
            a0 += bf2f((unsigned short)v);
            a1 += bf2f((unsigned short)(v >> 16));
        }
        unsigned int xv = *(const unsigned int*)(Xb + base * EMB + e0);
        const float m = mask[base];
        s0 += fmaxf(bf2f((unsigned short)xv)         + a0 * 0.0625f, 0.f) * m;
        s1 += fmaxf(bf2f((unsigned short)(xv >> 16)) + a1 * 0.0625f, 0.f) * m;
    }

    // in-block reduce: 4 group-partials -> chunk_pool[128] in sred[0][*]
    __shared__ float sred[4][EMB];
    sred[g][e0]     = s0;
    sred[g][e0 + 1] = s1;
    __syncthreads();
    const int t = threadIdx.x;
    if (t < EMB) {
        // thread t owns column t exclusively: read rows 0..3, write row 0 — no race
        sred[0][t] = sred[0][t] + sred[1][t] + sred[2][t] + sred[3][t];
    }
    __syncthreads();

    // chunk_pool @ W2 -> atomicAdd into out[b][*]
    if (t < EMB) {
        float r = 0.f;
        #pragma unroll 8
        for (int f = 0; f < EMB; ++f) r += sred[0][f] * W2[f * EMB + t];
        atomicAdd(&out[b * EMB + t], r);
    }
}

extern "C" void kernel_launch(void* const* d_in, const int* in_sizes, int n_in,
                              void* d_out, int out_size, void* d_ws, size_t ws_size,
                              hipStream_t stream)
{
    const float* word  = (const float*)d_in[0];
    const int*   nbr   = (const int*)  d_in[1];
    const float* mask  = (const float*)d_in[2];
    const float* W_enc = (const float*)d_in[3];
    const float* b_enc = (const float*)d_in[4];
    const float* W2    = (const float*)d_in[5];
    float* out = (float*)d_out;

    unsigned short* wt = (unsigned short*)d_ws;          // [2][128][128] bf16, 64 KB
    unsigned short* Xb = wt + 2 * EMB * EMB;             // [32768][128] bf16, 8 MB
    unsigned short* Yb = Xb + (size_t)R_TOT * EMB;       // [32768][128] bf16, 8 MB

    prep_w        <<<16,         256, 0, stream>>>(W_enc, wt, out);
    dual_gemm     <<<R_TOT / 64, 256, 0, stream>>>(word, wt, b_enc, Xb, Yb);
    gather_pool_w2<<<B_SZ * 16,  256, 0, stream>>>(Xb, Yb, nbr, mask, W2, out);
}

// Round 10
// 34.740 us; speedup vs baseline: 3.4791x; 1.0611x over previous
//
#include <hip/hip_runtime.h>
#include <hip/hip_bf16.h>

#define B_SZ  64
#define N_SZ  512
#define K_SZ  16
#define EMB   128
#define R_TOT (B_SZ * N_SZ)   // 32768 rows

typedef __attribute__((ext_vector_type(8))) short bf16x8;
typedef __attribute__((ext_vector_type(4))) float f32x4;

// XOR-swizzled u16 index into a [*][128]-u16 LDS tile (16B-unit granularity).
#define SWZ(row, col) ((((row) << 7)) + ((((col) >> 3) ^ ((row) & 15)) << 3) + ((col) & 7))

static __device__ __forceinline__ unsigned short f2bf(float x) {
    __hip_bfloat16 h = __float2bfloat16(x);   // RNE
    return *reinterpret_cast<unsigned short*>(&h);
}
static __device__ __forceinline__ float bf2f(unsigned short u) {
    union { unsigned int u32; float f; } c; c.u32 = ((unsigned int)u) << 16; return c.f;
}

// Fused: X = word@Wtop + bias (store bf16, pre-relu); Y = relu(X)@Wbot (store bf16).
// B-fragments are built DIRECTLY from W_enc via per-lane scalar loads: for a wave,
// lanes span 16 consecutive cols x 4 rows -> fully coalesced 64B segments, L2-hot.
// No weight-prep kernel, no sW tile. LDS = two 16KB A-tiles (word, relu(X)).
// First 32 blocks also zero d_out (gather accumulates into it atomically).
// XCD-affine block map: batch b's 8 row-blocks run on XCD b&7 (matches gather).
__global__ __launch_bounds__(256) void dual_gemm(const float* __restrict__ word,
                                                 const float* __restrict__ W_enc,
                                                 const float* __restrict__ bias,
                                                 unsigned short* __restrict__ Xb,
                                                 unsigned short* __restrict__ Yb,
                                                 float* __restrict__ out)
{
    __shared__ unsigned short sA0[64 * EMB];   // 16 KB, bf16(word) tile, swizzled
    __shared__ unsigned short sA1[64 * EMB];   // 16 KB, relu(X) tile, swizzled
    const int tid = threadIdx.x;

    // bid -> (batch, row-chunk) with batch&7 == bid&7 (XCD heuristic: bid%8)
    const int bid    = blockIdx.x;
    const int xcd    = bid & 7;
    const int j      = bid >> 3;            // 0..63
    const int b      = xcd + 8 * (j & 7);   // 0..63, b&7 == xcd
    const int rchunk = j >> 3;              // 0..7
    const int block_row = b * N_SZ + rchunk * 64;

    if (bid < 32) out[bid * 256 + tid] = 0.f;        // zero the 8192-float accumulator

    for (int i = tid; i < 2048; i += 256) {          // A tile f32 -> bf16
        int r = i >> 5, c4 = i & 31;
        float4 v = ((const float4*)(word + (size_t)(block_row + r) * EMB))[c4];
        unsigned short o[4] = { f2bf(v.x), f2bf(v.y), f2bf(v.z), f2bf(v.w) };
        *(uint2*)&sA0[SWZ(r, c4 * 4)] = *(uint2*)o;
    }

    const int lane  = tid & 63;
    const int w     = tid >> 6;
    const int l15   = lane & 15;
    const int g     = lane >> 4;                 // 0..3
    const int ncol0 = w * 32;

    // B fragments for GEMM1 straight from W_enc: frag[j] = W_enc[ks*32+g*8+j][col]
    bf16x8 bfr[2][4];
    #pragma unroll
    for (int nb = 0; nb < 2; ++nb) {
        const int col = ncol0 + nb * 16 + l15;
        #pragma unroll
        for (int ks = 0; ks < 4; ++ks) {
            unsigned short t[8];
            #pragma unroll
            for (int jj = 0; jj < 8; ++jj)
                t[jj] = f2bf(W_enc[(size_t)(ks * 32 + g * 8 + jj) * EMB + col]);
            bfr[nb][ks] = *(bf16x8*)t;
        }
    }

    f32x4 acc[4][2];
    #pragma unroll
    for (int mb = 0; mb < 4; ++mb)
        #pragma unroll
        for (int nb = 0; nb < 2; ++nb)
            acc[mb][nb] = (f32x4){0.f, 0.f, 0.f, 0.f};

    __syncthreads();   // sA0 staged

    // ---- GEMM1: sA0 @ Wtop ----
    #pragma unroll
    for (int ks = 0; ks < 4; ++ks) {
        bf16x8 a[4];
        #pragma unroll
        for (int mb = 0; mb < 4; ++mb)
            a[mb] = *(const bf16x8*)&sA0[SWZ(mb * 16 + l15, ks * 32 + g * 8)];
        #pragma unroll
        for (int mb = 0; mb < 4; ++mb)
            #pragma unroll
            for (int nb = 0; nb < 2; ++nb)
                acc[mb][nb] = __builtin_amdgcn_mfma_f32_16x16x32_bf16(a[mb], bfr[nb][ks], acc[mb][nb], 0, 0, 0);
    }

    // prefetch GEMM2 B fragments (Wbot = rows 128..255), overlaps epilogue stores
    bf16x8 bfr2[2][4];
    #pragma unroll
    for (int nb = 0; nb < 2; ++nb) {
        const int col = ncol0 + nb * 16 + l15;
        #pragma unroll
        for (int ks = 0; ks < 4; ++ks) {
            unsigned short t[8];
            #pragma unroll
            for (int jj = 0; jj < 8; ++jj)
                t[jj] = f2bf(W_enc[(size_t)(128 + ks * 32 + g * 8 + jj) * EMB + col]);
            bfr2[nb][ks] = *(bf16x8*)t;
        }
    }

    // epilogue 1: X = acc + bias; store Xb (pre-relu); relu into sA1
    #pragma unroll
    for (int mb = 0; mb < 4; ++mb) {
        #pragma unroll
        for (int nb = 0; nb < 2; ++nb) {
            const int col = ncol0 + nb * 16 + l15;
            const float bv = bias[col];
            #pragma unroll
            for (int r = 0; r < 4; ++r) {
                const int row_l = mb * 16 + g * 4 + r;
                float x = acc[mb][nb][r] + bv;
                Xb[(size_t)(block_row + row_l) * EMB + col] = f2bf(x);
                sA1[SWZ(row_l, col)] = f2bf(fmaxf(x, 0.f));
            }
            acc[mb][nb] = (f32x4){0.f, 0.f, 0.f, 0.f};
        }
    }
    __syncthreads();   // sA1 complete

    // ---- GEMM2: relu(X) @ Wbot ----
    #pragma unroll
    for (int ks = 0; ks < 4; ++ks) {
        bf16x8 a[4];
        #pragma unroll
        for (int mb = 0; mb < 4; ++mb)
            a[mb] = *(const bf16x8*)&sA1[SWZ(mb * 16 + l15, ks * 32 + g * 8)];
        #pragma unroll
        for (int mb = 0; mb < 4; ++mb)
            #pragma unroll
            for (int nb = 0; nb < 2; ++nb)
                acc[mb][nb] = __builtin_amdgcn_mfma_f32_16x16x32_bf16(a[mb], bfr2[nb][ks], acc[mb][nb], 0, 0, 0);
    }
    #pragma unroll
    for (int mb = 0; mb < 4; ++mb)
        #pragma unroll
        for (int nb = 0; nb < 2; ++nb) {
            const int col = ncol0 + nb * 16 + l15;
            #pragma unroll
            for (int r = 0; r < 4; ++r) {
                const int row_l = mb * 16 + g * 4 + r;
                Yb[(size_t)(block_row + row_l) * EMB + col] = f2bf(acc[mb][nb][r]);
            }
        }
}

// Per (b,chunk): 4 groups of 64 lanes; group g sums mask*relu(X + mean_k Y[nb])
// over its 8 n's. In-block reduce -> chunk_pool (128), multiply by W2,
// atomicAdd the 128-float result into out[b]. XCD swizzle: batch b on XCD b&7
// (matches dual_gemm's producer map -> Y/X reads hit the local L2).
__global__ __launch_bounds__(256) void gather_pool_w2(const unsigned short* __restrict__ Xb,
                                                      const unsigned short* __restrict__ Yb,
                                                      const int*   __restrict__ nbr,
                                                      const float* __restrict__ mask,
                                                      const float* __restrict__ W2,
                                                      float* __restrict__ out)
{
    const int bid   = blockIdx.x;
    const int xcd   = bid & 7;
    const int rest  = bid >> 3;
    const int chunk = rest & 15;
    const int b     = (rest >> 4) * 8 + xcd;
    const int g     = threadIdx.x >> 6;        // 4 groups of 64 lanes
    const int lane  = threadIdx.x & 63;
    const int e0    = lane * 2;
    const unsigned short* Yb_b = Yb + (size_t)b * N_SZ * EMB;

    float s0 = 0.f, s1 = 0.f;
    for (int nn = 0; nn < 8; ++nn) {
        const int n = chunk * 32 + g * 8 + nn;
        const long base = (long)b * N_SZ + n;
        const int* idx = nbr + base * K_SZ;
        int id[K_SZ];
        #pragma unroll
        for (int k = 0; k < K_SZ; ++k) id[k] = idx[k];
        float a0 = 0.f, a1 = 0.f;
        #pragma unroll
        for (int k = 0; k < K_SZ; ++k) {
            unsigned int v = *(const unsigned int*)(Yb_b + (size_t)id[k] * EMB + e0);
            a0 += bf2f((unsigned short)v);
            a1 += bf2f((unsigned short)(v >> 16));
        }
        unsigned int xv = *(const unsigned int*)(Xb + base * EMB + e0);
        const float m = mask[base];
        s0 += fmaxf(bf2f((unsigned short)xv)         + a0 * 0.0625f, 0.f) * m;
        s1 += fmaxf(bf2f((unsigned short)(xv >> 16)) + a1 * 0.0625f, 0.f) * m;
    }

    // in-block reduce: 4 group-partials -> chunk_pool[128] in sred[0][*]
    __shared__ float sred[4][EMB];
    sred[g][e0]     = s0;
    sred[g][e0 + 1] = s1;
    __syncthreads();
    const int t = threadIdx.x;
    if (t < EMB) {
        // thread t owns column t exclusively: read rows 0..3, write row 0 — no race
        sred[0][t] = sred[0][t] + sred[1][t] + sred[2][t] + sred[3][t];
    }
    __syncthreads();

    // chunk_pool @ W2 -> atomicAdd into out[b][*]
    if (t < EMB) {
        float r = 0.f;
        #pragma unroll 8
        for (int f = 0; f < EMB; ++f) r += sred[0][f] * W2[f * EMB + t];
        atomicAdd(&out[b * EMB + t], r);
    }
}

extern "C" void kernel_launch(void* const* d_in, const int* in_sizes, int n_in,
                              void* d_out, int out_size, void* d_ws, size_t ws_size,
                              hipStream_t stream)
{
    const float* word  = (const float*)d_in[0];
    const int*   nbr   = (const int*)  d_in[1];
    const float* mask  = (const float*)d_in[2];
    const float* W_enc = (const float*)d_in[3];
    const float* b_enc = (const float*)d_in[4];
    const float* W2    = (const float*)d_in[5];
    float* out = (float*)d_out;

    unsigned short* Xb = (unsigned short*)d_ws;          // [32768][128] bf16, 8 MB
    unsigned short* Yb = Xb + (size_t)R_TOT * EMB;       // [32768][128] bf16, 8 MB

    dual_gemm     <<<R_TOT / 64, 256, 0, stream>>>(word, W_enc, b_enc, Xb, Yb, out);
    gather_pool_w2<<<B_SZ * 16,  256, 0, stream>>>(Xb, Yb, nbr, mask, W2, out);
}